// Round 4
// baseline (528.585 us; speedup 1.0000x reference)
//
#include <hip/hip_runtime.h>

#define BB    4
#define NN    8192
#define KK    16
#define CIN   64
#define COUTC 64
#define P     16           // points per block (= MFMA M-tile)

typedef short bf16x8 __attribute__((ext_vector_type(8)));
typedef float f32x4  __attribute__((ext_vector_type(4)));

__device__ __forceinline__ unsigned short f2bf_rne(float f) {
    unsigned int u = __builtin_bit_cast(unsigned int, f);
    u += 0x7fffu + ((u >> 16) & 1u);
    return (unsigned short)(u >> 16);
}

__device__ __forceinline__ unsigned int pack_bf2(float lo, float hi) {
    return (unsigned int)f2bf_rne(lo) | ((unsigned int)f2bf_rne(hi) << 16);
}

// Wt[cout][g], g = pass*512 + cin*8 + ml  (logical m = pass*8 + ml), 1/16 folded.
__global__ __launch_bounds__(256) void prep_w(const float* __restrict__ W,
                                              unsigned short* __restrict__ Wt) {
    const int o    = blockIdx.x * 256 + threadIdx.x;   // 65536 total
    const int cout = o >> 10;
    const int g    = o & 1023;
    const int pass = g >> 9;
    const int q    = g & 511;
    const int cin  = q >> 3;
    const int m    = pass * 8 + (q & 7);
    Wt[o] = f2bf_rne(W[(cin * 16 + m) * 64 + cout] * (1.0f / 16.0f));
}

// folded layer-1: A1[j] = {a0,a1,a2,b'} per hidden unit j
__global__ void prep_fold(const float* __restrict__ l1w, const float* __restrict__ l1b,
                          const float* __restrict__ centers, float* __restrict__ A1) {
    const int t = threadIdx.x;     // 32 threads
    float bb = l1b[t];
    float a0 = 0.f, a1 = 0.f, a2 = 0.f;
    for (int c = 0; c < 16; ++c) {
        const float w0 = l1w[(c     ) * 32 + t];
        const float w1 = l1w[(16 + c) * 32 + t];
        const float w2 = l1w[(32 + c) * 32 + t];
        a0 += w0; a1 += w1; a2 += w2;
        bb -= centers[c] * w0 + centers[16 + c] * w1 + centers[32 + c] * w2;
    }
    A1[t * 4 + 0] = a0; A1[t * 4 + 1] = a1; A1[t * 4 + 2] = a2; A1[t * 4 + 3] = bb;
}

__global__ __launch_bounds__(256, 4) void ptconv_fused(
    const float* __restrict__ inp,       // [B,N,CIN]
    const float* __restrict__ points,    // [B,N,3]
    const float* __restrict__ next_pts,  // [B,N,3]
    const int*   __restrict__ indices,   // [B,N,K]
    const unsigned short* __restrict__ Wt, // [COUT][1024] bf16 (prep, reordered)
    const float* __restrict__ A1f,       // [32][4] folded layer-1 (prep)
    const float* __restrict__ bias,      // [COUT]
    const float* __restrict__ l2w, const float* __restrict__ l2b,  // [32,16],[16]
    const float* __restrict__ l3w, const float* __restrict__ l3b,  // [16,16],[16]
    float* __restrict__ out)             // [B,N,COUT]
{
    const int t    = threadIdx.x;
    const int lane = t & 63;
    const int w    = t >> 6;             // wave id 0..3
    const int pt0  = blockIdx.x * P;
    const int b    = pt0 >> 13;          // pt0 / NN

    __shared__ float s_A1[32][4];        // 512 B
    __shared__ float s_w2[32][16];       // 2 KB
    __shared__ float s_w3[16][16];       // 1 KB
    __shared__ float s_b2[16], s_b3[16];
    __shared__ int   s_idx[P][KK];       // 1 KB
    __shared__ float s_nxt[P][3];
    __shared__ float s_h3[P][264];       // 16.5 KB, row: k*16 + ((m+k)&15)
    __shared__ unsigned short s_fb[P][512]; // 16 KB bf16, k'' = cin*8+ml, XOR-swizzled

    // ---------------- setup ----------------
    if (t < 128) ((float*)s_A1)[t] = A1f[t];
    for (int i = t; i < 512; i += 256) ((float*)s_w2)[i] = l2w[i];
    if (t < 256) ((float*)s_w3)[t] = l3w[t];
    if (t < 16)  { s_b2[t] = l2b[t]; s_b3[t] = l3b[t]; }
    ((int*)s_idx)[t] = indices[(size_t)pt0 * KK + t];     // 256 = P*KK
    if (t < P * 3) ((float*)s_nxt)[t] = next_pts[(size_t)pt0 * 3 + t];
    __syncthreads();

    // ---------------- phase 1: MLP, thread = (p,k) ----------------
    {
        const int p = t >> 4, k = t & 15;
        const int id = s_idx[p][k];
        const float* pp = points + ((size_t)(b * NN + id)) * 3;
        const float px = pp[0] - s_nxt[p][0];
        const float py = pp[1] - s_nxt[p][1];
        const float pz = pp[2] - s_nxt[p][2];
        float h1[32];
        #pragma unroll
        for (int j = 0; j < 32; ++j) {
            const float4 a = *(const float4*)&s_A1[j][0];
            h1[j] = fmaxf(fmaf(px, a.x, fmaf(py, a.y, fmaf(pz, a.z, a.w))), 0.f);
        }
        float h2[16];
        #pragma unroll
        for (int j = 0; j < 16; ++j) h2[j] = s_b2[j];
        #pragma unroll
        for (int i = 0; i < 32; ++i) {
            const float4 q0 = *(const float4*)&s_w2[i][0];
            const float4 q1 = *(const float4*)&s_w2[i][4];
            const float4 q2 = *(const float4*)&s_w2[i][8];
            const float4 q3 = *(const float4*)&s_w2[i][12];
            h2[0]  = fmaf(h1[i], q0.x, h2[0]);  h2[1]  = fmaf(h1[i], q0.y, h2[1]);
            h2[2]  = fmaf(h1[i], q0.z, h2[2]);  h2[3]  = fmaf(h1[i], q0.w, h2[3]);
            h2[4]  = fmaf(h1[i], q1.x, h2[4]);  h2[5]  = fmaf(h1[i], q1.y, h2[5]);
            h2[6]  = fmaf(h1[i], q1.z, h2[6]);  h2[7]  = fmaf(h1[i], q1.w, h2[7]);
            h2[8]  = fmaf(h1[i], q2.x, h2[8]);  h2[9]  = fmaf(h1[i], q2.y, h2[9]);
            h2[10] = fmaf(h1[i], q2.z, h2[10]); h2[11] = fmaf(h1[i], q2.w, h2[11]);
            h2[12] = fmaf(h1[i], q3.x, h2[12]); h2[13] = fmaf(h1[i], q3.y, h2[13]);
            h2[14] = fmaf(h1[i], q3.z, h2[14]); h2[15] = fmaf(h1[i], q3.w, h2[15]);
        }
        #pragma unroll
        for (int j = 0; j < 16; ++j) h2[j] = fmaxf(h2[j], 0.f);
        float h3[16];
        #pragma unroll
        for (int j = 0; j < 16; ++j) h3[j] = s_b3[j];
        #pragma unroll
        for (int i = 0; i < 16; ++i) {
            const float4 q0 = *(const float4*)&s_w3[i][0];
            const float4 q1 = *(const float4*)&s_w3[i][4];
            const float4 q2 = *(const float4*)&s_w3[i][8];
            const float4 q3 = *(const float4*)&s_w3[i][12];
            h3[0]  = fmaf(h2[i], q0.x, h3[0]);  h3[1]  = fmaf(h2[i], q0.y, h3[1]);
            h3[2]  = fmaf(h2[i], q0.z, h3[2]);  h3[3]  = fmaf(h2[i], q0.w, h3[3]);
            h3[4]  = fmaf(h2[i], q1.x, h3[4]);  h3[5]  = fmaf(h2[i], q1.y, h3[5]);
            h3[6]  = fmaf(h2[i], q1.z, h3[6]);  h3[7]  = fmaf(h2[i], q1.w, h3[7]);
            h3[8]  = fmaf(h2[i], q2.x, h3[8]);  h3[9]  = fmaf(h2[i], q2.y, h3[9]);
            h3[10] = fmaf(h2[i], q2.z, h3[10]); h3[11] = fmaf(h2[i], q2.w, h3[11]);
            h3[12] = fmaf(h2[i], q3.x, h3[12]); h3[13] = fmaf(h2[i], q3.y, h3[13]);
            h3[14] = fmaf(h2[i], q3.z, h3[14]); h3[15] = fmaf(h2[i], q3.w, h3[15]);
        }
        // rotated write: position (m+k)&15 holds h3[m]
        #pragma unroll
        for (int m = 0; m < 16; ++m)
            s_h3[p][k * 16 + ((m + k) & 15)] = fmaxf(h3[m], 0.f);
    }
    __syncthreads();

    // ---------------- phase 2: f[p][cin][m], lane = cin ----------------
    uint4 hold[4];                        // half-2 bf16 (m=8..15) per owned point
    {
        #pragma unroll
        for (int j = 0; j < 4; ++j) {
            const int p2 = w * 4 + j;
            float fv[16];
            #pragma unroll
            for (int k = 0; k < 16; ++k)
                fv[k] = inp[((size_t)(b * NN + s_idx[p2][k])) * 64 + lane];
            float accf[16];
            #pragma unroll
            for (int m = 0; m < 16; ++m) accf[m] = 0.f;
            #pragma unroll
            for (int k = 0; k < 16; ++k) {
                const float* hr = &s_h3[p2][k * 16];
                float hv[16];
                #pragma unroll
                for (int q = 0; q < 4; ++q) {
                    const float4 qq = *(const float4*)(hr + q * 4);
                    hv[q * 4 + 0] = qq.x; hv[q * 4 + 1] = qq.y;
                    hv[q * 4 + 2] = qq.z; hv[q * 4 + 3] = qq.w;
                }
                #pragma unroll
                for (int m = 0; m < 16; ++m)
                    accf[m] = fmaf(fv[k], hv[(m + k) & 15], accf[m]);
            }
            unsigned int pk[8];
            #pragma unroll
            for (int i = 0; i < 8; ++i)
                pk[i] = pack_bf2(accf[2 * i], accf[2 * i + 1]);
            hold[j] = make_uint4(pk[4], pk[5], pk[6], pk[7]);
            char* fbb = (char*)s_fb;
            const unsigned int off =
                ((unsigned)(p2 * 1024 + lane * 16)) ^ ((unsigned)(p2 & 7) << 4);
            *(uint4*)(fbb + off) = make_uint4(pk[0], pk[1], pk[2], pk[3]);
        }
    }
    __syncthreads();

    // ---------------- phase 3: MFMA over two k''-halves ----------------
    {
        const int arow = lane & 15;      // A row = point ; also B col = cout_local
        const int hi   = lane >> 4;
        const unsigned int abase = (unsigned)arow * 1024u + (unsigned)hi * 16u;
        const unsigned int xr    = (unsigned)(arow & 7) << 4;
        const unsigned short* wb = Wt + (size_t)(w * 16 + arow) * 1024 + hi * 8;
        const char* fbb = (const char*)s_fb;
        f32x4 acc = {0.f, 0.f, 0.f, 0.f};
        #pragma unroll
        for (int kk = 0; kk < 16; ++kk) {
            const bf16x8 av = *(const bf16x8*)(fbb + ((abase + (unsigned)kk * 64u) ^ xr));
            const bf16x8 bv = *(const bf16x8*)(wb + kk * 32);
            acc = __builtin_amdgcn_mfma_f32_16x16x32_bf16(av, bv, acc, 0, 0, 0);
        }
        __syncthreads();                 // everyone done reading half-1
        #pragma unroll
        for (int j = 0; j < 4; ++j) {
            const int p2 = w * 4 + j;
            char* fbw = (char*)s_fb;
            const unsigned int off =
                ((unsigned)(p2 * 1024 + lane * 16)) ^ ((unsigned)(p2 & 7) << 4);
            *(uint4*)(fbw + off) = hold[j];
        }
        __syncthreads();                 // half-2 visible
        #pragma unroll
        for (int kk = 0; kk < 16; ++kk) {
            const bf16x8 av = *(const bf16x8*)(fbb + ((abase + (unsigned)kk * 64u) ^ xr));
            const bf16x8 bv = *(const bf16x8*)(wb + 512 + kk * 32);
            acc = __builtin_amdgcn_mfma_f32_16x16x32_bf16(av, bv, acc, 0, 0, 0);
        }
        const float bvs = bias[w * 16 + arow];
        #pragma unroll
        for (int r = 0; r < 4; ++r)
            out[((size_t)(pt0 + hi * 4 + r)) * 64 + w * 16 + arow] = acc[r] + bvs;
    }
}

extern "C" void kernel_launch(void* const* d_in, const int* in_sizes, int n_in,
                              void* d_out, int out_size, void* d_ws, size_t ws_size,
                              hipStream_t stream) {
    const float* inp      = (const float*)d_in[0];
    const float* points   = (const float*)d_in[1];
    const float* next_pts = (const float*)d_in[2];
    const int*   indices  = (const int*)  d_in[3];
    const float* weight   = (const float*)d_in[4];
    const float* bias     = (const float*)d_in[5];
    const float* centers  = (const float*)d_in[6];
    const float* l1w      = (const float*)d_in[7];
    const float* l1b      = (const float*)d_in[8];
    const float* l2w      = (const float*)d_in[9];
    const float* l2b      = (const float*)d_in[10];
    const float* l3w      = (const float*)d_in[11];
    const float* l3b      = (const float*)d_in[12];
    float* outp = (float*)d_out;

    unsigned short* Wt  = (unsigned short*)d_ws;            // 128 KB
    float*          A1f = (float*)((char*)d_ws + 131072);   // 512 B

    prep_w<<<256, 256, 0, stream>>>(weight, Wt);
    prep_fold<<<1, 32, 0, stream>>>(l1w, l1b, centers, A1f);

    const int grid = (BB * NN) / P;               // 2048 blocks
    ptconv_fused<<<grid, 256, 0, stream>>>(inp, points, next_pts, indices,
                                           Wt, A1f, bias,
                                           l2w, l2b, l3w, l3b, outp);
}

// Round 6
// 97.259 us; speedup vs baseline: 5.4348x; 5.4348x over previous
//
#include <hip/hip_runtime.h>

#define BB    4
#define NN    8192
#define KK    16
#define CIN   64
#define COUTC 64
#define P     16           // points per block (= MFMA M-tile)

typedef short bf16x8 __attribute__((ext_vector_type(8)));
typedef float f32x4  __attribute__((ext_vector_type(4)));

__device__ __forceinline__ unsigned short f2bf_rne(float f) {
    unsigned int u = __builtin_bit_cast(unsigned int, f);
    u += 0x7fffu + ((u >> 16) & 1u);
    return (unsigned short)(u >> 16);
}

__device__ __forceinline__ unsigned int pack_bf2(float lo, float hi) {
    return (unsigned int)f2bf_rne(lo) | ((unsigned int)f2bf_rne(hi) << 16);
}

// Wt[cout][g], g = pass*512 + cin*8 + ml  (logical m = pass*8 + ml), 1/16 folded.
__global__ __launch_bounds__(256) void prep_w(const float* __restrict__ W,
                                              unsigned short* __restrict__ Wt) {
    const int o    = blockIdx.x * 256 + threadIdx.x;   // 65536 total
    const int cout = o >> 10;
    const int g    = o & 1023;
    const int pass = g >> 9;
    const int q    = g & 511;
    const int cin  = q >> 3;
    const int m    = pass * 8 + (q & 7);
    Wt[o] = f2bf_rne(W[(cin * 16 + m) * 64 + cout] * (1.0f / 16.0f));
}

// folded layer-1: A1[j] = {a0,a1,a2,b'} per hidden unit j
__global__ void prep_fold(const float* __restrict__ l1w, const float* __restrict__ l1b,
                          const float* __restrict__ centers, float* __restrict__ A1) {
    const int t = threadIdx.x;     // 32 threads
    float bb = l1b[t];
    float a0 = 0.f, a1 = 0.f, a2 = 0.f;
    for (int c = 0; c < 16; ++c) {
        const float w0 = l1w[(c     ) * 32 + t];
        const float w1 = l1w[(16 + c) * 32 + t];
        const float w2 = l1w[(32 + c) * 32 + t];
        a0 += w0; a1 += w1; a2 += w2;
        bb -= centers[c] * w0 + centers[16 + c] * w1 + centers[32 + c] * w2;
    }
    A1[t * 4 + 0] = a0; A1[t * 4 + 1] = a1; A1[t * 4 + 2] = a2; A1[t * 4 + 3] = bb;
}

__global__ __launch_bounds__(256, 2) void ptconv_fused(
    const float* __restrict__ inp,       // [B,N,CIN]
    const float* __restrict__ points,    // [B,N,3]
    const float* __restrict__ next_pts,  // [B,N,3]
    const int*   __restrict__ indices,   // [B,N,K]
    const unsigned short* __restrict__ Wt, // [COUT][1024] bf16 (prep, reordered)
    const float* __restrict__ A1f,       // [32][4] folded layer-1 (prep)
    const float* __restrict__ bias,      // [COUT]
    const float* __restrict__ l2w, const float* __restrict__ l2b,  // [32,16],[16]
    const float* __restrict__ l3w, const float* __restrict__ l3b,  // [16,16],[16]
    float* __restrict__ out)             // [B,N,COUT]
{
    const int t    = threadIdx.x;
    const int lane = t & 63;
    const int w    = t >> 6;             // wave id 0..3
    const int pt0  = blockIdx.x * P;
    const int b    = pt0 >> 13;          // pt0 / NN

    __shared__ float s_A1[32][4];        // 512 B
    __shared__ float s_w2[32][16];       // 2 KB
    __shared__ float s_w3[16][16];       // 1 KB
    __shared__ float s_b2[16], s_b3[16];
    __shared__ int   s_idx[P][KK];       // 1 KB
    __shared__ float s_nxt[P][3];
    __shared__ float s_h3[P][264];       // 16.9 KB, row: k*16 + ((m+k)&15)
    __shared__ unsigned short s_fb[P][512]; // 16 KB bf16 (one k''-half), XOR-swizzled
    // total ~38.4 KB -> 4 blocks/CU

    // ---------------- setup ----------------
    if (t < 128) ((float*)s_A1)[t] = A1f[t];
    for (int i = t; i < 512; i += 256) ((float*)s_w2)[i] = l2w[i];
    if (t < 256) ((float*)s_w3)[t] = l3w[t];
    if (t < 16)  { s_b2[t] = l2b[t]; s_b3[t] = l3b[t]; }
    ((int*)s_idx)[t] = indices[(size_t)pt0 * KK + t];     // 256 = P*KK
    if (t < P * 3) ((float*)s_nxt)[t] = next_pts[(size_t)pt0 * 3 + t];
    __syncthreads();

    // ---------------- phase 1: MLP, thread = (p,k) ----------------
    {
        const int p = t >> 4, k = t & 15;
        const int id = s_idx[p][k];
        const float* pp = points + ((size_t)(b * NN + id)) * 3;
        const float px = pp[0] - s_nxt[p][0];
        const float py = pp[1] - s_nxt[p][1];
        const float pz = pp[2] - s_nxt[p][2];
        float h1[32];
        #pragma unroll
        for (int j = 0; j < 32; ++j) {
            const float4 a = *(const float4*)&s_A1[j][0];
            h1[j] = fmaxf(fmaf(px, a.x, fmaf(py, a.y, fmaf(pz, a.z, a.w))), 0.f);
        }
        float h2[16];
        #pragma unroll
        for (int j = 0; j < 16; ++j) h2[j] = s_b2[j];
        #pragma unroll
        for (int i = 0; i < 32; ++i) {
            const float4 q0 = *(const float4*)&s_w2[i][0];
            const float4 q1 = *(const float4*)&s_w2[i][4];
            const float4 q2 = *(const float4*)&s_w2[i][8];
            const float4 q3 = *(const float4*)&s_w2[i][12];
            h2[0]  = fmaf(h1[i], q0.x, h2[0]);  h2[1]  = fmaf(h1[i], q0.y, h2[1]);
            h2[2]  = fmaf(h1[i], q0.z, h2[2]);  h2[3]  = fmaf(h1[i], q0.w, h2[3]);
            h2[4]  = fmaf(h1[i], q1.x, h2[4]);  h2[5]  = fmaf(h1[i], q1.y, h2[5]);
            h2[6]  = fmaf(h1[i], q1.z, h2[6]);  h2[7]  = fmaf(h1[i], q1.w, h2[7]);
            h2[8]  = fmaf(h1[i], q2.x, h2[8]);  h2[9]  = fmaf(h1[i], q2.y, h2[9]);
            h2[10] = fmaf(h1[i], q2.z, h2[10]); h2[11] = fmaf(h1[i], q2.w, h2[11]);
            h2[12] = fmaf(h1[i], q3.x, h2[12]); h2[13] = fmaf(h1[i], q3.y, h2[13]);
            h2[14] = fmaf(h1[i], q3.z, h2[14]); h2[15] = fmaf(h1[i], q3.w, h2[15]);
        }
        #pragma unroll
        for (int j = 0; j < 16; ++j) h2[j] = fmaxf(h2[j], 0.f);
        float h3[16];
        #pragma unroll
        for (int j = 0; j < 16; ++j) h3[j] = s_b3[j];
        #pragma unroll
        for (int i = 0; i < 16; ++i) {
            const float4 q0 = *(const float4*)&s_w3[i][0];
            const float4 q1 = *(const float4*)&s_w3[i][4];
            const float4 q2 = *(const float4*)&s_w3[i][8];
            const float4 q3 = *(const float4*)&s_w3[i][12];
            h3[0]  = fmaf(h2[i], q0.x, h3[0]);  h3[1]  = fmaf(h2[i], q0.y, h3[1]);
            h3[2]  = fmaf(h2[i], q0.z, h3[2]);  h3[3]  = fmaf(h2[i], q0.w, h3[3]);
            h3[4]  = fmaf(h2[i], q1.x, h3[4]);  h3[5]  = fmaf(h2[i], q1.y, h3[5]);
            h3[6]  = fmaf(h2[i], q1.z, h3[6]);  h3[7]  = fmaf(h2[i], q1.w, h3[7]);
            h3[8]  = fmaf(h2[i], q2.x, h3[8]);  h3[9]  = fmaf(h2[i], q2.y, h3[9]);
            h3[10] = fmaf(h2[i], q2.z, h3[10]); h3[11] = fmaf(h2[i], q2.w, h3[11]);
            h3[12] = fmaf(h2[i], q3.x, h3[12]); h3[13] = fmaf(h2[i], q3.y, h3[13]);
            h3[14] = fmaf(h2[i], q3.z, h3[14]); h3[15] = fmaf(h2[i], q3.w, h3[15]);
        }
        // rotated write: position (m+k)&15 holds h3[m]
        #pragma unroll
        for (int m = 0; m < 16; ++m)
            s_h3[p][k * 16 + ((m + k) & 15)] = fmaxf(h3[m], 0.f);
    }
    __syncthreads();

    // ---------------- phase 2: f[p][cin][m], lane = cin ----------------
    uint4 hold[4];                        // half-2 bf16 (m=8..15) per owned point
    {
        #pragma unroll
        for (int j = 0; j < 4; ++j) {
            const int p2 = w * 4 + j;
            float accf[16];
            #pragma unroll
            for (int m = 0; m < 16; ++m) accf[m] = 0.f;
            #pragma unroll
            for (int k = 0; k < 16; ++k) {
                const int id = s_idx[p2][k];
                const float fv = inp[((size_t)(b * NN + id)) * 64 + lane];
                const float* hr = &s_h3[p2][k * 16];
                float hv[16];
                #pragma unroll
                for (int q = 0; q < 4; ++q) {
                    const float4 qq = *(const float4*)(hr + q * 4);
                    hv[q * 4 + 0] = qq.x; hv[q * 4 + 1] = qq.y;
                    hv[q * 4 + 2] = qq.z; hv[q * 4 + 3] = qq.w;
                }
                #pragma unroll
                for (int m = 0; m < 16; ++m)
                    accf[m] = fmaf(fv, hv[(m + k) & 15], accf[m]);
            }
            unsigned int pk[8];
            #pragma unroll
            for (int i = 0; i < 8; ++i)
                pk[i] = pack_bf2(accf[2 * i], accf[2 * i + 1]);
            hold[j] = make_uint4(pk[4], pk[5], pk[6], pk[7]);
            char* fbb = (char*)s_fb;
            const unsigned int off =
                ((unsigned)(p2 * 1024 + lane * 16)) ^ ((unsigned)(p2 & 7) << 4);
            *(uint4*)(fbb + off) = make_uint4(pk[0], pk[1], pk[2], pk[3]);
        }
    }
    __syncthreads();

    // ---------------- phase 3: MFMA over two k''-halves ----------------
    {
        const int arow = lane & 15;      // A row = point ; also B col = cout_local
        const int hi   = lane >> 4;
        const unsigned int abase = (unsigned)arow * 1024u + (unsigned)hi * 16u;
        const unsigned int xr    = (unsigned)(arow & 7) << 4;
        const unsigned short* wb = Wt + (size_t)(w * 16 + arow) * 1024 + hi * 8;
        const char* fbb = (const char*)s_fb;
        f32x4 acc = {0.f, 0.f, 0.f, 0.f};
        #pragma unroll
        for (int kk = 0; kk < 16; ++kk) {
            const bf16x8 av = *(const bf16x8*)(fbb + ((abase + (unsigned)kk * 64u) ^ xr));
            const bf16x8 bv = *(const bf16x8*)(wb + kk * 32);
            acc = __builtin_amdgcn_mfma_f32_16x16x32_bf16(av, bv, acc, 0, 0, 0);
        }
        __syncthreads();                 // everyone done reading half-1
        #pragma unroll
        for (int j = 0; j < 4; ++j) {
            const int p2 = w * 4 + j;
            char* fbw = (char*)s_fb;
            const unsigned int off =
                ((unsigned)(p2 * 1024 + lane * 16)) ^ ((unsigned)(p2 & 7) << 4);
            *(uint4*)(fbw + off) = hold[j];
        }
        __syncthreads();                 // half-2 visible
        #pragma unroll
        for (int kk = 0; kk < 16; ++kk) {
            const bf16x8 av = *(const bf16x8*)(fbb + ((abase + (unsigned)kk * 64u) ^ xr));
            const bf16x8 bv = *(const bf16x8*)(wb + 512 + kk * 32);
            acc = __builtin_amdgcn_mfma_f32_16x16x32_bf16(av, bv, acc, 0, 0, 0);
        }
        const float bvs = bias[w * 16 + arow];
        #pragma unroll
        for (int r = 0; r < 4; ++r)
            out[((size_t)(pt0 + hi * 4 + r)) * 64 + w * 16 + arow] = acc[r] + bvs;
    }
}

extern "C" void kernel_launch(void* const* d_in, const int* in_sizes, int n_in,
                              void* d_out, int out_size, void* d_ws, size_t ws_size,
                              hipStream_t stream) {
    const float* inp      = (const float*)d_in[0];
    const float* points   = (const float*)d_in[1];
    const float* next_pts = (const float*)d_in[2];
    const int*   indices  = (const int*)  d_in[3];
    const float* weight   = (const float*)d_in[4];
    const float* bias     = (const float*)d_in[5];
    const float* centers  = (const float*)d_in[6];
    const float* l1w      = (const float*)d_in[7];
    const float* l1b      = (const float*)d_in[8];
    const float* l2w      = (const float*)d_in[9];
    const float* l2b      = (const float*)d_in[10];
    const float* l3w      = (const float*)d_in[11];
    const float* l3b      = (const float*)d_in[12];
    float* outp = (float*)d_out;

    unsigned short* Wt  = (unsigned short*)d_ws;            // 128 KB
    float*          A1f = (float*)((char*)d_ws + 131072);   // 512 B

    prep_w<<<256, 256, 0, stream>>>(weight, Wt);
    prep_fold<<<1, 32, 0, stream>>>(l1w, l1b, centers, A1f);

    const int grid = (BB * NN) / P;               // 2048 blocks
    ptconv_fused<<<grid, 256, 0, stream>>>(inp, points, next_pts, indices,
                                           Wt, A1f, bias,
                                           l2w, l2b, l3w, l3b, outp);
}